// Round 1
// baseline (188.876 us; speedup 1.0000x reference)
//
#include <hip/hip_runtime.h>
#include <climits>

using short8 = __attribute__((ext_vector_type(8))) short;
using f32x4  = __attribute__((ext_vector_type(4))) float;
typedef unsigned short u16;

#define BATCH 8192
#define TDIM  384
#define GDIM  256

// ---------- helpers ----------
__device__ __forceinline__ u16 f2bf(float x) {
  unsigned u = __float_as_uint(x);
  unsigned r = (u + 0x7FFFu + ((u >> 16) & 1u)) >> 16;  // RTNE
  return (u16)r;
}

__device__ __forceinline__ void gload16(u16* lds, const u16* src) {
  __builtin_amdgcn_global_load_lds(
      (const __attribute__((address_space(1))) void*)src,
      (__attribute__((address_space(3))) void*)lds, 16, 0, 0);
}

// ---------- 1. normalize text rows, split into bf16 hi/lo ----------
__global__ void prep_text(const float* __restrict__ text,
                          u16* __restrict__ tHi, u16* __restrict__ tLo) {
  const int lane = threadIdx.x & 63;
  const int wid  = threadIdx.x >> 6;
  const int row  = blockIdx.x * 4 + wid;
  const float* x = text + row * TDIM;
  float v[6];
  float ss = 0.f;
#pragma unroll
  for (int q = 0; q < 6; ++q) { v[q] = x[lane + q * 64]; ss += v[q] * v[q]; }
#pragma unroll
  for (int m = 1; m < 64; m <<= 1) ss += __shfl_xor(ss, m);
  const float scale = 1.0f / fmaxf(sqrtf(ss), 1e-12f);
#pragma unroll
  for (int q = 0; q < 6; ++q) {
    float t = v[q] * scale;
    u16 hi = f2bf(t);
    float fhi = __uint_as_float(((unsigned)hi) << 16);
    u16 lo = f2bf(t - fhi);
    tHi[row * TDIM + lane + q * 64] = hi;
    tLo[row * TDIM + lane + q * 64] = lo;
  }
}

// ---------- 2. fp32 -> bf16 elementwise ----------
__global__ void cvt_bf16(const float* __restrict__ in, u16* __restrict__ out, int n4) {
  int i = blockIdx.x * blockDim.x + threadIdx.x;
  if (i < n4) {
    float4 v = ((const float4*)in)[i];
    ushort4 o;
    o.x = f2bf(v.x); o.y = f2bf(v.y); o.z = f2bf(v.z); o.w = f2bf(v.w);
    ((ushort4*)out)[i] = o;
  }
}

// ---------- 3. g_pre = graph @ W^T + b  (bf16 MFMA, single pass) ----------
__global__ __launch_bounds__(256) void gemm1(const u16* __restrict__ gHi,
                                             const u16* __restrict__ wHi,
                                             const float* __restrict__ bias,
                                             float* __restrict__ g) {
  __shared__ u16 sA[128 * 32];
  __shared__ u16 sB[128 * 32];
  const int tid = threadIdx.x;
  const int lane = tid & 63, wid = tid >> 6;
  const int l15 = lane & 15, l4 = lane >> 4;
  const int wrb = (wid >> 1) * 64, wcb = (wid & 1) * 64;
  const int iBase = blockIdx.x * 128, jBase = blockIdx.y * 128;
  const int sRow = tid >> 2, sS = (tid & 3) * 8;

  f32x4 acc[4][4];
#pragma unroll
  for (int i = 0; i < 4; ++i)
#pragma unroll
    for (int j = 0; j < 4; ++j) acc[i][j] = (f32x4){0.f, 0.f, 0.f, 0.f};

  for (int ks = 0; ks < GDIM / 32; ++ks) {
    const int kB = ks * 32;
    __syncthreads();
    gload16(&sA[tid * 8],        gHi + (size_t)(iBase + sRow) * GDIM + kB + sS);
    gload16(&sA[2048 + tid * 8], gHi + (size_t)(iBase + 64 + sRow) * GDIM + kB + sS);
    gload16(&sB[tid * 8],        wHi + (size_t)(jBase + sRow) * GDIM + kB + sS);
    gload16(&sB[2048 + tid * 8], wHi + (size_t)(jBase + 64 + sRow) * GDIM + kB + sS);
    __syncthreads();
    short8 a[4], b[4];
#pragma unroll
    for (int f = 0; f < 4; ++f) {
      a[f] = *(const short8*)&sA[(wrb + f * 16 + l15) * 32 + l4 * 8];
      b[f] = *(const short8*)&sB[(wcb + f * 16 + l15) * 32 + l4 * 8];
    }
#pragma unroll
    for (int i = 0; i < 4; ++i)
#pragma unroll
      for (int j = 0; j < 4; ++j)
        acc[i][j] = __builtin_amdgcn_mfma_f32_16x16x32_bf16(a[i], b[j], acc[i][j], 0, 0, 0);
  }
#pragma unroll
  for (int j = 0; j < 4; ++j) {
    const int col = jBase + wcb + j * 16 + l15;
    const float bv = bias[col];
#pragma unroll
    for (int i = 0; i < 4; ++i)
#pragma unroll
      for (int r = 0; r < 4; ++r) {
        const int row = iBase + wrb + i * 16 + l4 * 4 + r;
        g[(size_t)row * TDIM + col] = acc[i][j][r] + bv;
      }
  }
}

// ---------- 4. in-place l2-normalize rows of g ----------
__global__ void norm_g(float* __restrict__ g) {
  const int lane = threadIdx.x & 63;
  const int wid  = threadIdx.x >> 6;
  const int row  = blockIdx.x * 4 + wid;
  float* x = g + (size_t)row * TDIM;
  float v[6];
  float ss = 0.f;
#pragma unroll
  for (int q = 0; q < 6; ++q) { v[q] = x[lane + q * 64]; ss += v[q] * v[q]; }
#pragma unroll
  for (int m = 1; m < 64; m <<= 1) ss += __shfl_xor(ss, m);
  const float scale = 1.0f / fmaxf(sqrtf(ss), 1e-12f);
#pragma unroll
  for (int q = 0; q < 6; ++q) x[lane + q * 64] = v[q] * scale;
}

// ---------- 5. sim = t@t.T fused with per-row argmax/argmin (bf16x3) ----------
// grid (64 row-blocks, 8 col-chunks of 1024). Partials: [row][chunk*2 + wavecolhalf]
__global__ __launch_bounds__(256, 2) void simk(const u16* __restrict__ tHi,
                                               const u16* __restrict__ tLo,
                                               int* __restrict__ pMax,
                                               int* __restrict__ pMin) {
  __shared__ u16 sAhi[128 * 32], sAlo[128 * 32], sBhi[128 * 32], sBlo[128 * 32];
  const int tid = threadIdx.x;
  const int lane = tid & 63, wid = tid >> 6;
  const int l15 = lane & 15, l4 = lane >> 4;
  const int wrb = (wid >> 1) * 64, wcb = (wid & 1) * 64;
  const int rBase = blockIdx.x * 128;
  const int chunk = blockIdx.y;
  const int sRow = tid >> 2, sS = (tid & 3) * 8;

  int keyMax[16], keyMin[16];
#pragma unroll
  for (int i = 0; i < 16; ++i) { keyMax[i] = INT_MIN; keyMin[i] = INT_MAX; }

  for (int ct = 0; ct < 8; ++ct) {
    const int cBase = chunk * 1024 + ct * 128;
    f32x4 acc[4][4];
#pragma unroll
    for (int i = 0; i < 4; ++i)
#pragma unroll
      for (int j = 0; j < 4; ++j) acc[i][j] = (f32x4){0.f, 0.f, 0.f, 0.f};

    for (int ks = 0; ks < TDIM / 32; ++ks) {
      const int kB = ks * 32;
      __syncthreads();
      gload16(&sAhi[tid * 8],        tHi + (size_t)(rBase + sRow) * TDIM + kB + sS);
      gload16(&sAhi[2048 + tid * 8], tHi + (size_t)(rBase + 64 + sRow) * TDIM + kB + sS);
      gload16(&sAlo[tid * 8],        tLo + (size_t)(rBase + sRow) * TDIM + kB + sS);
      gload16(&sAlo[2048 + tid * 8], tLo + (size_t)(rBase + 64 + sRow) * TDIM + kB + sS);
      gload16(&sBhi[tid * 8],        tHi + (size_t)(cBase + sRow) * TDIM + kB + sS);
      gload16(&sBhi[2048 + tid * 8], tHi + (size_t)(cBase + 64 + sRow) * TDIM + kB + sS);
      gload16(&sBlo[tid * 8],        tLo + (size_t)(cBase + sRow) * TDIM + kB + sS);
      gload16(&sBlo[2048 + tid * 8], tLo + (size_t)(cBase + 64 + sRow) * TDIM + kB + sS);
      __syncthreads();
      short8 ah[4], al[4], bh[4], bl[4];
#pragma unroll
      for (int f = 0; f < 4; ++f) {
        const int ao = (wrb + f * 16 + l15) * 32 + l4 * 8;
        const int bo = (wcb + f * 16 + l15) * 32 + l4 * 8;
        ah[f] = *(const short8*)&sAhi[ao];
        al[f] = *(const short8*)&sAlo[ao];
        bh[f] = *(const short8*)&sBhi[bo];
        bl[f] = *(const short8*)&sBlo[bo];
      }
#pragma unroll
      for (int i = 0; i < 4; ++i)
#pragma unroll
        for (int j = 0; j < 4; ++j) {
          acc[i][j] = __builtin_amdgcn_mfma_f32_16x16x32_bf16(ah[i], bh[j], acc[i][j], 0, 0, 0);
          acc[i][j] = __builtin_amdgcn_mfma_f32_16x16x32_bf16(ah[i], bl[j], acc[i][j], 0, 0, 0);
          acc[i][j] = __builtin_amdgcn_mfma_f32_16x16x32_bf16(al[i], bh[j], acc[i][j], 0, 0, 0);
        }
    }
    // fold this 128-col tile into running keys
    const bool diagTile = (cBase == rBase);
#pragma unroll
    for (int i = 0; i < 4; ++i)
#pragma unroll
      for (int j = 0; j < 4; ++j) {
        const int cIdx = cBase + wcb + j * 16 + l15;
        const int cmaxT = 8191 - cIdx;
        f32x4 v = acc[i][j];
#pragma unroll
        for (int r = 0; r < 4; ++r) {
          const int qv = (int)(v[r] * 131072.0f);
          int km = qv * 8192 + cmaxT;
          int kn = qv * 8192 + cIdx;
          if (diagTile) {
            const int grow = rBase + wrb + i * 16 + l4 * 4 + r;
            if (grow == cIdx) { km = cmaxT; kn = INT_MAX; }  // masked diag: max sees 0, min sees +inf
          }
          const int s = i * 4 + r;
          keyMax[s] = max(keyMax[s], km);
          keyMin[s] = min(keyMin[s], kn);
        }
      }
  }
  // reduce across the 16 column-lanes, write per-(row, chunk, colhalf) partials
#pragma unroll
  for (int s = 0; s < 16; ++s) {
    int km = keyMax[s], kn = keyMin[s];
#pragma unroll
    for (int m = 1; m < 16; m <<= 1) {
      km = max(km, __shfl_xor(km, m));
      kn = min(kn, __shfl_xor(kn, m));
    }
    if (l15 == 0) {
      const int i = s >> 2, r = s & 3;
      const int row = rBase + wrb + i * 16 + l4 * 4 + r;
      pMax[row * 16 + chunk * 2 + (wid & 1)] = km;
      pMin[row * 16 + chunk * 2 + (wid & 1)] = kn;
    }
  }
}

// ---------- 6. merge partials, gather g rows, per-row triplet loss ----------
__global__ void loss_rows(const float* __restrict__ g, const int* __restrict__ pMax,
                          const int* __restrict__ pMin, float* __restrict__ losses) {
  const int lane = threadIdx.x & 63;
  const int wid  = threadIdx.x >> 6;
  const int row  = blockIdx.x * 4 + wid;
  int km = (lane < 16) ? pMax[row * 16 + lane] : INT_MIN;
  int kn = (lane < 16) ? pMin[row * 16 + lane] : INT_MAX;
#pragma unroll
  for (int m = 1; m < 16; m <<= 1) {
    km = max(km, __shfl_xor(km, m));
    kn = min(kn, __shfl_xor(kn, m));
  }
  km = __shfl(km, 0);
  kn = __shfl(kn, 0);
  const int pos = 8191 - (km & 8191);
  const int neg = kn & 8191;
  const float* ga = g + (size_t)row * TDIM;
  const float* gp = g + (size_t)pos * TDIM;
  const float* gn = g + (size_t)neg * TDIM;
  float pd = 0.f, nd = 0.f;
#pragma unroll
  for (int q = 0; q < 6; ++q) {
    const int o = lane + q * 64;
    const float a = ga[o];
    const float dp = a - gp[o]; pd += dp * dp;
    const float dn = a - gn[o]; nd += dn * dn;
  }
#pragma unroll
  for (int m = 1; m < 64; m <<= 1) {
    pd += __shfl_xor(pd, m);
    nd += __shfl_xor(nd, m);
  }
  if (lane == 0) losses[row] = fmaxf(pd - nd + 0.5f, 0.0f);
}

// ---------- 7. deterministic mean ----------
__global__ void final_reduce(const float* __restrict__ losses, float* __restrict__ out) {
  __shared__ float red[256];
  float s = 0.f;
  for (int i = threadIdx.x; i < BATCH; i += 256) s += losses[i];
  red[threadIdx.x] = s;
  __syncthreads();
  for (int w = 128; w > 0; w >>= 1) {
    if (threadIdx.x < w) red[threadIdx.x] += red[threadIdx.x + w];
    __syncthreads();
  }
  if (threadIdx.x == 0) out[0] = red[0] * (1.0f / (float)BATCH);
}

extern "C" void kernel_launch(void* const* d_in, const int* in_sizes, int n_in,
                              void* d_out, int out_size, void* d_ws, size_t ws_size,
                              hipStream_t stream) {
  const float* graph = (const float*)d_in[0];
  const float* text  = (const float*)d_in[1];
  const float* W     = (const float*)d_in[2];
  const float* bias  = (const float*)d_in[3];
  float* out = (float*)d_out;
  char* ws = (char*)d_ws;

  u16*  tHi    = (u16*)(ws);                 // 8192*384*2  = 6291456
  u16*  tLo    = (u16*)(ws + 6291456);       // 6291456
  u16*  gHi    = (u16*)(ws + 12582912);      // 8192*256*2  = 4194304
  u16*  wHi    = (u16*)(ws + 16777216);      // 384*256*2   = 196608
  float* g     = (float*)(ws + 16973824);    // 8192*384*4  = 12582912
  int*  pMax   = (int*)(ws + 29556736);      // 8192*16*4   = 524288
  int*  pMin   = (int*)(ws + 30081024);      // 524288
  float* losses = (float*)(ws + 30605312);   // 8192*4

  prep_text<<<dim3(2048), dim3(256), 0, stream>>>(text, tHi, tLo);
  cvt_bf16<<<dim3(2048), dim3(256), 0, stream>>>(graph, gHi, 524288);
  cvt_bf16<<<dim3(96), dim3(256), 0, stream>>>(W, wHi, 24576);
  gemm1<<<dim3(64, 3), dim3(256), 0, stream>>>(gHi, wHi, bias, g);
  norm_g<<<dim3(2048), dim3(256), 0, stream>>>(g);
  simk<<<dim3(64, 8), dim3(256), 0, stream>>>(tHi, tLo, pMax, pMin);
  loss_rows<<<dim3(2048), dim3(256), 0, stream>>>(g, pMax, pMin, losses);
  final_reduce<<<dim3(1), dim3(256), 0, stream>>>(losses, out);
}

// Round 2
// 160.019 us; speedup vs baseline: 1.1803x; 1.1803x over previous
//
#include <hip/hip_runtime.h>
#include <climits>
#include <math.h>

using short8 = __attribute__((ext_vector_type(8))) short;
using f32x4  = __attribute__((ext_vector_type(4))) float;
typedef unsigned short u16;

#define BATCH 8192
#define TDIM  384
#define GDIM  256

// ---------- helpers ----------
__device__ __forceinline__ u16 f2bf(float x) {
  unsigned u = __float_as_uint(x);
  unsigned r = (u + 0x7FFFu + ((u >> 16) & 1u)) >> 16;  // RTNE
  return (u16)r;
}

__device__ __forceinline__ void gload16(u16* lds, const u16* src) {
  __builtin_amdgcn_global_load_lds(
      (const __attribute__((address_space(1))) void*)src,
      (__attribute__((address_space(3))) void*)lds, 16, 0, 0);
}

// ---------- 1. normalize text rows, split into bf16 hi/lo ----------
__global__ void prep_text(const float* __restrict__ text,
                          u16* __restrict__ tHi, u16* __restrict__ tLo) {
  const int lane = threadIdx.x & 63;
  const int wid  = threadIdx.x >> 6;
  const int row  = blockIdx.x * 4 + wid;
  const float* x = text + row * TDIM;
  float v[6];
  float ss = 0.f;
#pragma unroll
  for (int q = 0; q < 6; ++q) { v[q] = x[lane + q * 64]; ss += v[q] * v[q]; }
#pragma unroll
  for (int m = 1; m < 64; m <<= 1) ss += __shfl_xor(ss, m);
  const float scale = 1.0f / fmaxf(sqrtf(ss), 1e-12f);
#pragma unroll
  for (int q = 0; q < 6; ++q) {
    float t = v[q] * scale;
    u16 hi = f2bf(t);
    float fhi = __uint_as_float(((unsigned)hi) << 16);
    u16 lo = f2bf(t - fhi);
    tHi[row * TDIM + lane + q * 64] = hi;
    tLo[row * TDIM + lane + q * 64] = lo;
  }
}

// ---------- 2. fp32 -> bf16 elementwise ----------
__global__ void cvt_bf16(const float* __restrict__ in, u16* __restrict__ out, int n4) {
  int i = blockIdx.x * blockDim.x + threadIdx.x;
  if (i < n4) {
    float4 v = ((const float4*)in)[i];
    ushort4 o;
    o.x = f2bf(v.x); o.y = f2bf(v.y); o.z = f2bf(v.z); o.w = f2bf(v.w);
    ((ushort4*)out)[i] = o;
  }
}

// ---------- 3. init key arrays ----------
__global__ void init_keys(int* __restrict__ gMax, int* __restrict__ gMin) {
  const int i = blockIdx.x * 256 + threadIdx.x;
  gMax[i] = INT_MIN;
  gMin[i] = INT_MAX;
}

// ---------- 4. g_pre = graph @ W^T + b  (bf16 MFMA, single pass) ----------
__global__ __launch_bounds__(256) void gemm1(const u16* __restrict__ gHi,
                                             const u16* __restrict__ wHi,
                                             const float* __restrict__ bias,
                                             float* __restrict__ g) {
  __shared__ u16 sA[128 * 32];
  __shared__ u16 sB[128 * 32];
  const int tid = threadIdx.x;
  const int lane = tid & 63, wid = tid >> 6;
  const int l15 = lane & 15, l4 = lane >> 4;
  const int wrb = (wid >> 1) * 64, wcb = (wid & 1) * 64;
  const int iBase = blockIdx.x * 128, jBase = blockIdx.y * 128;
  const int sRow = tid >> 2, sS = (tid & 3) * 8;

  f32x4 acc[4][4];
#pragma unroll
  for (int i = 0; i < 4; ++i)
#pragma unroll
    for (int j = 0; j < 4; ++j) acc[i][j] = (f32x4){0.f, 0.f, 0.f, 0.f};

  for (int ks = 0; ks < GDIM / 32; ++ks) {
    const int kB = ks * 32;
    __syncthreads();
    gload16(&sA[tid * 8],        gHi + (size_t)(iBase + sRow) * GDIM + kB + sS);
    gload16(&sA[2048 + tid * 8], gHi + (size_t)(iBase + 64 + sRow) * GDIM + kB + sS);
    gload16(&sB[tid * 8],        wHi + (size_t)(jBase + sRow) * GDIM + kB + sS);
    gload16(&sB[2048 + tid * 8], wHi + (size_t)(jBase + 64 + sRow) * GDIM + kB + sS);
    __syncthreads();
    short8 a[4], b[4];
#pragma unroll
    for (int f = 0; f < 4; ++f) {
      a[f] = *(const short8*)&sA[(wrb + f * 16 + l15) * 32 + l4 * 8];
      b[f] = *(const short8*)&sB[(wcb + f * 16 + l15) * 32 + l4 * 8];
    }
#pragma unroll
    for (int i = 0; i < 4; ++i)
#pragma unroll
      for (int j = 0; j < 4; ++j)
        acc[i][j] = __builtin_amdgcn_mfma_f32_16x16x32_bf16(a[i], b[j], acc[i][j], 0, 0, 0);
  }
#pragma unroll
  for (int j = 0; j < 4; ++j) {
    const int col = jBase + wcb + j * 16 + l15;
    const float bv = bias[col];
#pragma unroll
    for (int i = 0; i < 4; ++i)
#pragma unroll
      for (int r = 0; r < 4; ++r) {
        const int row = iBase + wrb + i * 16 + l4 * 4 + r;
        g[(size_t)row * TDIM + col] = acc[i][j][r] + bv;
      }
  }
}

// ---------- 5. in-place l2-normalize rows of g ----------
__global__ void norm_g(float* __restrict__ g) {
  const int lane = threadIdx.x & 63;
  const int wid  = threadIdx.x >> 6;
  const int row  = blockIdx.x * 4 + wid;
  float* x = g + (size_t)row * TDIM;
  float v[6];
  float ss = 0.f;
#pragma unroll
  for (int q = 0; q < 6; ++q) { v[q] = x[lane + q * 64]; ss += v[q] * v[q]; }
#pragma unroll
  for (int m = 1; m < 64; m <<= 1) ss += __shfl_xor(ss, m);
  const float scale = 1.0f / fmaxf(sqrtf(ss), 1e-12f);
#pragma unroll
  for (int q = 0; q < 6; ++q) x[lane + q * 64] = v[q] * scale;
}

// ---------- 6. sim = t@t.T upper-triangle tiles, fused argmax/argmin (bf16x3) ----------
// One 128x128 tile per block; 2080 blocks enumerate bi<=bj. Each tile folds into
// row keys (direct) and column keys (transposed, skipped on diagonal tiles) via
// deterministic atomicMax/atomicMin on packed int keys.
__global__ __launch_bounds__(256, 4) void simk(const u16* __restrict__ tHi,
                                               const u16* __restrict__ tLo,
                                               int* __restrict__ gMax,
                                               int* __restrict__ gMin) {
  __shared__ u16 sAhi[128 * 32], sAlo[128 * 32], sBhi[128 * 32], sBlo[128 * 32];
  const int tid = threadIdx.x;
  const int lane = tid & 63, wid = tid >> 6;
  const int l15 = lane & 15, l4 = lane >> 4;
  const int wrb = (wid >> 1) * 64, wcb = (wid & 1) * 64;
  const int sRow = tid >> 2, sS = (tid & 3) * 8;

  // decode upper-triangle tile index: off(b) = b*(129-b)/2
  const int t = blockIdx.x;
  int bi = (int)((129.0 - sqrt(16641.0 - 8.0 * (double)t)) * 0.5);
  while (bi * (129 - bi) / 2 > t) --bi;
  while ((bi + 1) * (129 - (bi + 1)) / 2 <= t) ++bi;
  const int bj = bi + (t - bi * (129 - bi) / 2);
  const int rBase = bi * 128, cBase = bj * 128;
  const bool diagT = (bi == bj);

  f32x4 acc[4][4];
#pragma unroll
  for (int i = 0; i < 4; ++i)
#pragma unroll
    for (int j = 0; j < 4; ++j) acc[i][j] = (f32x4){0.f, 0.f, 0.f, 0.f};

  for (int ks = 0; ks < TDIM / 32; ++ks) {
    const int kB = ks * 32;
    __syncthreads();
    gload16(&sAhi[tid * 8],        tHi + (size_t)(rBase + sRow) * TDIM + kB + sS);
    gload16(&sAhi[2048 + tid * 8], tHi + (size_t)(rBase + 64 + sRow) * TDIM + kB + sS);
    gload16(&sAlo[tid * 8],        tLo + (size_t)(rBase + sRow) * TDIM + kB + sS);
    gload16(&sAlo[2048 + tid * 8], tLo + (size_t)(rBase + 64 + sRow) * TDIM + kB + sS);
    gload16(&sBhi[tid * 8],        tHi + (size_t)(cBase + sRow) * TDIM + kB + sS);
    gload16(&sBhi[2048 + tid * 8], tHi + (size_t)(cBase + 64 + sRow) * TDIM + kB + sS);
    gload16(&sBlo[tid * 8],        tLo + (size_t)(cBase + sRow) * TDIM + kB + sS);
    gload16(&sBlo[2048 + tid * 8], tLo + (size_t)(cBase + 64 + sRow) * TDIM + kB + sS);
    __syncthreads();
    short8 ah[4], al[4], bh[4], bl[4];
#pragma unroll
    for (int f = 0; f < 4; ++f) {
      const int ao = (wrb + f * 16 + l15) * 32 + l4 * 8;
      const int bo = (wcb + f * 16 + l15) * 32 + l4 * 8;
      ah[f] = *(const short8*)&sAhi[ao];
      al[f] = *(const short8*)&sAlo[ao];
      bh[f] = *(const short8*)&sBhi[bo];
      bl[f] = *(const short8*)&sBlo[bo];
    }
#pragma unroll
    for (int i = 0; i < 4; ++i)
#pragma unroll
      for (int j = 0; j < 4; ++j) {
        acc[i][j] = __builtin_amdgcn_mfma_f32_16x16x32_bf16(ah[i], bh[j], acc[i][j], 0, 0, 0);
        acc[i][j] = __builtin_amdgcn_mfma_f32_16x16x32_bf16(ah[i], bl[j], acc[i][j], 0, 0, 0);
        acc[i][j] = __builtin_amdgcn_mfma_f32_16x16x32_bf16(al[i], bh[j], acc[i][j], 0, 0, 0);
      }
  }

  // ---- fold tile into packed int keys (epilogue-only registers) ----
  int keyMax[16], keyMin[16], keyMaxT[4], keyMinT[4];
#pragma unroll
  for (int s = 0; s < 16; ++s) { keyMax[s] = INT_MIN; keyMin[s] = INT_MAX; }
#pragma unroll
  for (int j = 0; j < 4; ++j) { keyMaxT[j] = INT_MIN; keyMinT[j] = INT_MAX; }

#pragma unroll
  for (int i = 0; i < 4; ++i)
#pragma unroll
    for (int j = 0; j < 4; ++j) {
      const int cIdx = cBase + wcb + j * 16 + l15;
#pragma unroll
      for (int r = 0; r < 4; ++r) {
        const int grow = rBase + wrb + i * 16 + l4 * 4 + r;
        const int qv = (int)(acc[i][j][r] * 131072.0f);
        int km = qv * 8192 + (8191 - cIdx);
        int kn = qv * 8192 + cIdx;
        if (diagT && grow == cIdx) { km = 8191 - cIdx; kn = INT_MAX; }  // diag: max sees 0, min sees +inf
        const int s = i * 4 + r;
        keyMax[s] = max(keyMax[s], km);
        keyMin[s] = min(keyMin[s], kn);
        if (!diagT) {
          const int kmT = qv * 8192 + (8191 - grow);
          const int knT = qv * 8192 + grow;
          keyMaxT[j] = max(keyMaxT[j], kmT);
          keyMinT[j] = min(keyMinT[j], knT);
        }
      }
    }

  // direct: reduce across 16 column-lanes, atomics per row
#pragma unroll
  for (int s = 0; s < 16; ++s) {
    int km = keyMax[s], kn = keyMin[s];
#pragma unroll
    for (int m = 1; m < 16; m <<= 1) {
      km = max(km, __shfl_xor(km, m));
      kn = min(kn, __shfl_xor(kn, m));
    }
    if (l15 == 0) {
      const int row = rBase + wrb + (s >> 2) * 16 + l4 * 4 + (s & 3);
      atomicMax(&gMax[row], km);
      atomicMin(&gMin[row], kn);
    }
  }
  // transposed: reduce across the 4 l4-groups, atomics per column
  if (!diagT) {
#pragma unroll
    for (int j = 0; j < 4; ++j) {
      int km = keyMaxT[j], kn = keyMinT[j];
      km = max(km, __shfl_xor(km, 16)); kn = min(kn, __shfl_xor(kn, 16));
      km = max(km, __shfl_xor(km, 32)); kn = min(kn, __shfl_xor(kn, 32));
      if (l4 == 0) {
        const int colp = cBase + wcb + j * 16 + l15;
        atomicMax(&gMax[colp], km);
        atomicMin(&gMin[colp], kn);
      }
    }
  }
}

// ---------- 7. gather g rows, per-row triplet loss ----------
__global__ void loss_rows(const float* __restrict__ g, const int* __restrict__ gMax,
                          const int* __restrict__ gMin, float* __restrict__ losses) {
  const int lane = threadIdx.x & 63;
  const int wid  = threadIdx.x >> 6;
  const int row  = blockIdx.x * 4 + wid;
  const int pos = 8191 - (gMax[row] & 8191);
  const int neg = gMin[row] & 8191;
  const float* ga = g + (size_t)row * TDIM;
  const float* gp = g + (size_t)pos * TDIM;
  const float* gn = g + (size_t)neg * TDIM;
  float pd = 0.f, nd = 0.f;
#pragma unroll
  for (int q = 0; q < 6; ++q) {
    const int o = lane + q * 64;
    const float a = ga[o];
    const float dp = a - gp[o]; pd += dp * dp;
    const float dn = a - gn[o]; nd += dn * dn;
  }
#pragma unroll
  for (int m = 1; m < 64; m <<= 1) {
    pd += __shfl_xor(pd, m);
    nd += __shfl_xor(nd, m);
  }
  if (lane == 0) losses[row] = fmaxf(pd - nd + 0.5f, 0.0f);
}

// ---------- 8. deterministic mean ----------
__global__ void final_reduce(const float* __restrict__ losses, float* __restrict__ out) {
  __shared__ float red[256];
  float s = 0.f;
  for (int i = threadIdx.x; i < BATCH; i += 256) s += losses[i];
  red[threadIdx.x] = s;
  __syncthreads();
  for (int w = 128; w > 0; w >>= 1) {
    if (threadIdx.x < w) red[threadIdx.x] += red[threadIdx.x + w];
    __syncthreads();
  }
  if (threadIdx.x == 0) out[0] = red[0] * (1.0f / (float)BATCH);
}

extern "C" void kernel_launch(void* const* d_in, const int* in_sizes, int n_in,
                              void* d_out, int out_size, void* d_ws, size_t ws_size,
                              hipStream_t stream) {
  const float* graph = (const float*)d_in[0];
  const float* text  = (const float*)d_in[1];
  const float* W     = (const float*)d_in[2];
  const float* bias  = (const float*)d_in[3];
  float* out = (float*)d_out;
  char* ws = (char*)d_ws;

  u16*  tHi    = (u16*)(ws);                 // 8192*384*2  = 6291456
  u16*  tLo    = (u16*)(ws + 6291456);       // 6291456
  u16*  gHi    = (u16*)(ws + 12582912);      // 8192*256*2  = 4194304
  u16*  wHi    = (u16*)(ws + 16777216);      // 384*256*2   = 196608
  float* g     = (float*)(ws + 16973824);    // 8192*384*4  = 12582912
  int*  gMax   = (int*)(ws + 29556736);      // 8192*4 = 32768
  int*  gMin   = (int*)(ws + 29589504);      // 32768
  float* losses = (float*)(ws + 29622272);   // 32768

  prep_text<<<dim3(2048), dim3(256), 0, stream>>>(text, tHi, tLo);
  cvt_bf16<<<dim3(2048), dim3(256), 0, stream>>>(graph, gHi, 524288);
  cvt_bf16<<<dim3(96), dim3(256), 0, stream>>>(W, wHi, 24576);
  init_keys<<<dim3(32), dim3(256), 0, stream>>>(gMax, gMin);
  gemm1<<<dim3(64, 3), dim3(256), 0, stream>>>(gHi, wHi, bias, g);
  norm_g<<<dim3(2048), dim3(256), 0, stream>>>(g);
  simk<<<dim3(2080), dim3(256), 0, stream>>>(tHi, tLo, gMax, gMin);
  loss_rows<<<dim3(2048), dim3(256), 0, stream>>>(g, gMax, gMin, losses);
  final_reduce<<<dim3(1), dim3(256), 0, stream>>>(losses, out);
}